// Round 5
// baseline (171.390 us; speedup 1.0000x reference)
//
#include <hip/hip_runtime.h>

#define T_STEPS 512
#define G_CELLS 4096
#define L_UHN   15
#define TILE    8                      // timesteps per LDS tile
#define NTILES  (T_STEPS / TILE)       // 64
#define TILE_F  (TILE * 256 * 3)       // floats per tile = 6144 (24 KB)
#define CHUNKS_PER_WAVE 6              // 24 KB / (4 waves * 1 KB)
#define NZF     1e-5f
#define LOG2E   1.44269504088896340736f
#define LOG2_10 3.32192809488736234787f

// raw gfx950 transcendental units: v_exp_f32 computes 2^x, v_log_f32 computes log2(x)
__device__ __forceinline__ float fexp2(float x) { return __builtin_amdgcn_exp2f(x); }
__device__ __forceinline__ float flog2(float x) { return __builtin_amdgcn_logf(x); }

__device__ __forceinline__ float fpow(float a, float b) {
    // a must be > 0
    return fexp2(b * flog2(a));
}
__device__ __forceinline__ float fexp(float x) {        // e^x
    return fexp2(x * LOG2E);
}
__device__ __forceinline__ float fsigmoid(float v) {
    return 1.0f / (1.0f + fexp(-v));
}
__device__ __forceinline__ float fdescale(float s, float lo, float hi) {
    return lo + s * (hi - lo);
}

typedef const __attribute__((address_space(1))) void* gbl_ptr_t;
typedef __attribute__((address_space(3))) void* lds_ptr_t;

// Stage one 24KB forcing tile (TILE rows x 256 cells x 3 f32) into LDS.
// Each row of the tile is 3 KB contiguous in global x. Wave w copies chunks
// [w*6, w*6+6) of 1 KB each; LDS dest is wave-uniform, HW adds lane*16.
__device__ __forceinline__ void stage_tile(const float* __restrict__ x,
                                           int tileIdx, int g0,
                                           float* dst, int wave, int lane) {
    #pragma unroll
    for (int i = 0; i < CHUNKS_PER_WAVE; ++i) {
        const int c    = wave * CHUNKS_PER_WAVE + i;
        const int row  = c / 3;
        const int part = c - row * 3;
        const char* gsrc = (const char*)(x + ((size_t)(tileIdx * TILE + row) * G_CELLS + (size_t)g0) * 3)
                           + part * 1024 + lane * 16;
        char* ldst = (char*)dst + c * 1024;   // wave-uniform base
        __builtin_amdgcn_global_load_lds((gbl_ptr_t)gsrc, (lds_ptr_t)ldst, 16, 0, 0);
    }
}

__global__ __launch_bounds__(256) void blend_scan_kernel(
    const float* __restrict__ x,       // (T, G, 3)
    const float* __restrict__ params,  // (T, G, 39)
    float* __restrict__ out)           // (T, G)
{
    __shared__ float tile[2][TILE_F];

    const int tid  = threadIdx.x;
    const int lane = tid & 63;
    const int wave = tid >> 6;
    const int g0   = blockIdx.x * 256;
    const int g    = g0 + tid;

    // ---- load raw params for this cell (last timestep) ----
    const float* pp = params + ((size_t)(T_STEPS - 1) * G_CELLS + (size_t)g) * 39;
    float raw[39];
    #pragma unroll
    for (int i = 0; i < 39; ++i) raw[i] = pp[i];

    // ---- unpack physical params ----
    const float ddf_min     = fdescale(fsigmoid(raw[0]),  0.0f, 20.0f);
    const float ddf_plus    = fdescale(fsigmoid(raw[1]),  0.0f, 20.0f);
    const float Kcum        = fdescale(fsigmoid(raw[2]),  0.01f, 0.2f);
    const float Kf          = fdescale(fsigmoid(raw[3]),  0.0f, 5.0f);
    const float exp_fe      = fdescale(fsigmoid(raw[4]),  0.0f, 1.0f);
    const float Tbf         = fdescale(fsigmoid(raw[5]), -5.0f, 2.0f);
    const float Ccum        = fdescale(fsigmoid(raw[6]),  0.005f, 0.05f);
    const float SWI         = fdescale(fsigmoid(raw[7]),  0.0f, 0.4f);
    const float Tbm         = fdescale(fsigmoid(raw[8]), -2.0f, 3.0f);
    const float fcmin       = fdescale(fsigmoid(raw[9]),  0.0f, 0.1f);
    const float fcmin_plus  = fdescale(fsigmoid(raw[10]), 0.01f, 0.25f);
    const float vmax        = fdescale(fsigmoid(raw[11]), 0.001f, 500.0f);
    const float hmets_alpha = fdescale(fsigmoid(raw[12]), 0.0f, 1.0f);
    const float vic_beta    = fdescale(fsigmoid(raw[13]), 0.1f, 3.0f);
    const float hbv_beta    = fdescale(fsigmoid(raw[14]), 0.5f, 3.0f);
    const float quickflow_k = fdescale(fsigmoid(raw[15]), -5.0f, -2.0f);
    const float quickflow_n = fdescale(fsigmoid(raw[16]), 0.5f, 2.0f);
    const float mmax        = fdescale(fsigmoid(raw[17]), 0.0f, 100.0f);
    const float lamb        = fdescale(fsigmoid(raw[18]), 5.0f, 10.0f);
    const float baseflow_k  = fdescale(fsigmoid(raw[19]), -5.0f, -1.0f);
    const float baseflow_n  = fdescale(fsigmoid(raw[20]), 0.5f, 2.0f);
    const float ET_eff      = fdescale(fsigmoid(raw[21]), 0.0f, 3.0f);
    const float cv2p        = fdescale(fsigmoid(raw[22]), 1e-5f, 0.02f);
    // raw[23] (coef_phreatic) unused by forward

    // ---- softmax weight groups (on raw values, like reference) ----
    float w1, w2, w3, w4, w5, w6, w7, w8, w9, w10, w11;
    {
        float m = fmaxf(fmaxf(raw[24], raw[25]), raw[26]);
        float e0 = fexp(raw[24] - m), e1 = fexp(raw[25] - m), e2 = fexp(raw[26] - m);
        float inv = 1.0f / (e0 + e1 + e2);
        w1 = e0 * inv; w2 = e1 * inv; w3 = e2 * inv;
    }
    {
        float m = fmaxf(fmaxf(raw[27], raw[28]), raw[29]);
        float e0 = fexp(raw[27] - m), e1 = fexp(raw[28] - m), e2 = fexp(raw[29] - m);
        float inv = 1.0f / (e0 + e1 + e2);
        w4 = e0 * inv; w5 = e1 * inv; w6 = e2 * inv;
    }
    {
        float m = fmaxf(fmaxf(raw[30], raw[31]), raw[32]);
        float e0 = fexp(raw[30] - m), e1 = fexp(raw[31] - m), e2 = fexp(raw[32] - m);
        float inv = 1.0f / (e0 + e1 + e2);
        w7 = e0 * inv; w8 = e1 * inv; w9 = e2 * inv;
    }
    {
        float m = fmaxf(raw[33], raw[34]);
        float e0 = fexp(raw[33] - m), e1 = fexp(raw[34] - m);
        float inv = 1.0f / (e0 + e1);
        w10 = e0 * inv; w11 = e1 * inv;
    }

    // ---- routing params + gamma unit hydrographs ----
    const float a1 = fdescale(fsigmoid(raw[35]), 0.3f, 20.0f);
    const float b1 = fdescale(fsigmoid(raw[36]), 0.01f, 5.0f);
    const float a2 = fdescale(fsigmoid(raw[37]), 0.5f, 13.0f);
    const float b2 = fdescale(fsigmoid(raw[38]), 0.15f, 1.5f);

    const float LOG2T[L_UHN] = {
        -1.0f, 0.58496250072116f, 1.32192809488736f, 1.80735492205760f,
        2.16992500144231f, 2.45943161863730f, 2.70043971814109f,
        2.90689059560852f, 3.08746284125034f, 3.24792751344359f,
        3.39231742277876f, 3.52356195605701f, 3.64385618977472f,
        3.75488750216347f, 3.85798099512757f };

    float uh1[L_UHN], uh2[L_UHN];
    {
        float rb1 = LOG2E / b1, rb2 = LOG2E / b2;
        float s1 = 0.0f, s2 = 0.0f;
        #pragma unroll
        for (int k = 0; k < L_UHN; ++k) {
            float tk = (float)k + 0.5f;
            float v1 = fexp2((a1 - 1.0f) * LOG2T[k] - tk * rb1);
            float v2 = fexp2((a2 - 1.0f) * LOG2T[k] - tk * rb2);
            uh1[k] = v1; uh2[k] = v2; s1 += v1; s2 += v2;
        }
        float i1 = 1.0f / s1, i2 = 1.0f / s2;
        #pragma unroll
        for (int k = 0; k < L_UHN; ++k) { uh1[k] *= i1; uh2[k] *= i2; }
    }

    // ---- per-cell loop constants ----
    const float ddfsum      = ddf_min + ddf_plus;
    const float ddfK        = ddf_min * Kcum;
    const float inv_vmax    = 1.0f / vmax;
    const float qk10        = fexp2(quickflow_k * LOG2_10);
    const float bk10        = fexp2(baseflow_k * LOG2_10);
    const float qf_top_coef = mmax * (vmax / quickflow_n) * fexp2(-quickflow_n * flog2(lamb));
    const float fcsum       = fcmin + fcmin_plus;
    const float c_b1        = w10 * bk10;
    const float c_b2        = w11 * bk10;
    const float w7qk        = w7 * qk10;

    // ---- state ----
    float sp1 = 0.f, lw1 = 0.f, cm1 = 0.f;
    float sp2 = 0.f, lw2 = 0.f, cm2 = 0.f;
    float sp3 = 0.f, cm3 = 0.f;
    float vad = 0.f, phr = 0.f;

    float fut[L_UHN];
    #pragma unroll
    for (int k = 0; k < L_UHN; ++k) fut[k] = 0.0f;

    // ---- prologue: stage tile 0 ----
    stage_tile(x, 0, g0, tile[0], wave, lane);

    for (int tb = 0; tb < NTILES; ++tb) {
        float* cur = tile[tb & 1];
        float* nxt = tile[(tb + 1) & 1];

        // issue next tile's loads (wraps to 0 on last iter to keep vmcnt uniform)
        stage_tile(x, (tb + 1) & (NTILES - 1), g0, nxt, wave, lane);

        // wait for THIS tile's 6 loads (leave the 6 just-issued in flight)
        asm volatile("s_waitcnt vmcnt(6)" ::: "memory");
        __builtin_amdgcn_s_barrier();

        #pragma unroll
        for (int j = 0; j < TILE; ++j) {
            const int t = tb * TILE + j;
            const float* cj = cur + j * 768 + tid * 3;
            const float prcp = cj[0], tm = cj[1], pet = cj[2];
            const float rain = (tm > 0.0f) ? prcp : 0.0f;
            const float snow = prcp - rain;
            const float frz_pot = fmaxf(Tbf - tm, NZF);

            // --- snobal_hbv ---
            float o1;
            {
                float ddf  = fminf(ddfsum, fmaf(ddfK, cm1, ddf_min));
                float pm   = fmaxf(ddf * (tm - Tbm), 0.0f);
                float rfz  = fminf(Kf * frz_pot, lw1);
                sp1 = sp1 + snow + rfz;
                float melt = fminf(pm, sp1 + snow + rfz);   // reference quirk: sp already updated
                cm1 = (sp1 > NZF) ? (cm1 + melt) : 0.0f;
                sp1 = fmaxf(sp1 - melt, NZF);
                float wret = SWI * sp1;
                float wtmp = lw1 + melt + rain;
                o1 = fmaxf(wtmp - wret, 0.0f);
                lw1 = (o1 > 0.0f) ? wret : wtmp;
            }

            // --- snobal_hmets ---
            float o2;
            {
                float ddf  = fminf(ddfsum, fmaf(ddfK, cm2, ddf_min));
                float pm   = fmaxf(ddf * (tm - Tbm), 0.0f);
                float pfz  = Kf * fpow(frz_pot, exp_fe);
                float rfz  = fminf(pfz, lw2);
                lw2 = lw2 - rfz;
                sp2 = sp2 + rfz;
                float melt = fminf(pm, sp2 + snow);
                sp2 = sp2 + snow - melt;
                cm2 = (sp2 > NZF) ? (cm2 + melt) : 0.0f;
                float wrf  = fmaxf(fcsum * (1.0f - Ccum * cm2), fcmin);
                float wret = wrf * sp2;
                float wtmp = lw2 + melt + rain;
                o2 = fmaxf(wtmp - wret, 0.0f);
                lw2 = (o2 > 0.0f) ? wret : wtmp;
                cm2 = (sp2 > NZF) ? (cm2 + melt) : 0.0f;    // reference quirk: cm updated twice
            }

            // --- snobal_simple ---
            float o3;
            {
                float ddf  = fminf(ddfsum, fmaf(ddfK, cm3, ddf_min));
                float pm   = fmaxf(ddf * (tm - Tbm), 0.0f);
                float melt = fminf(pm, sp3);
                sp3 = sp3 + snow - melt;
                o3 = melt + rain;
                cm3 = (sp3 > NZF) ? (cm3 + melt) : 0.0f;
            }

            // --- vadose / phreatic chain ---
            float rr = w1 * o1 + w2 * o2 + w3 * o3;
            float vv = vad * inv_vmax;
            float sprop = fminf(fmaxf(vv, NZF), 1.0f - NZF);
            float l1 = flog2(1.0f - sprop);
            float phbv = fexp2(hbv_beta * l1);
            float pvic = fexp2(vic_beta * l1);
            float inf = w4 * rr * phbv + w5 * rr * (1.0f - hmets_alpha * vv) + w6 * rr * (1.0f - pvic);
            inf = fminf(fmaxf(inf, 0.0f), rr);
            float surface = rr - inf;
            vad += inf;
            vv = vad * inv_vmax;
            sprop = fminf(fmaxf(vv, NZF), 1.0f - NZF);
            float et = fminf(pet * ET_eff * sprop, vad);
            vad -= et;
            float spq   = fexp2(quickflow_n * flog2(sprop));
            float qf_top = fminf(qf_top_coef * spq, vad);
            float qf_vic = fminf(mmax * spq, vad);
            float qf = fminf(w7qk * vad + w8 * qf_top + w9 * qf_vic, vad);
            vad -= qf;
            float perc = cv2p * vad;
            vad -= perc;
            phr += perc;
            float pb = fexp2(baseflow_n * flog2(fmaxf(phr, NZF)));
            float bf = fminf(c_b1 * phr + c_b2 * pb, phr);
            phr -= bf;

            const float qt = surface + qf;
            const float bt = bf;

            // --- fused routing: rolling 15-wide future window ---
            #pragma unroll
            for (int k = 0; k < L_UHN; ++k)
                fut[k] = fmaf(uh1[k], qt, fmaf(uh2[k], bt, fut[k]));
            out[(size_t)t * G_CELLS + g] = fut[0];
            #pragma unroll
            for (int k = 0; k < L_UHN - 1; ++k) fut[k] = fut[k + 1];
            fut[L_UHN - 1] = 0.0f;
        }

        // all waves done reading cur before next iteration re-stages it
        asm volatile("" ::: "memory");
        __builtin_amdgcn_s_barrier();
    }
}

extern "C" void kernel_launch(void* const* d_in, const int* in_sizes, int n_in,
                              void* d_out, int out_size, void* d_ws, size_t ws_size,
                              hipStream_t stream) {
    const float* x      = (const float*)d_in[0];
    const float* params = (const float*)d_in[1];
    float* out          = (float*)d_out;
    blend_scan_kernel<<<dim3(G_CELLS / 256), dim3(256), 0, stream>>>(x, params, out);
}